// Round 3
// baseline (121.161 us; speedup 1.0000x reference)
//
#include <hip/hip_runtime.h>
#include <math.h>

#define BS 2
#define C  32
#define H  256
#define W  256
#define HW (H * W)
#define PS 5

// f32(pi), matching JAX's rounding of np.pi to float32
#define PI_F 3.14159274101257324e+00f

// ws layout: 8 quarter-planes, (q, b, hw, 8ch). One (q,b) plane = 2.1 MB,
// comfortably inside one XCD's 4 MiB L2 together with its nnf slice.

// ---------------------------------------------------------------------------
// Kernel 1: transpose source (b, c, h, w) -> four quarter-planes (b, h*w, 8).
// Conflict-free LDS (bank = (ch+pl)%32), coalesced reads, 32B-chunk writes.
// ---------------------------------------------------------------------------
__global__ __launch_bounds__(256) void transpose_split4(
    const float* __restrict__ src, float* __restrict__ ws) {
    __shared__ float lds[C][64 + 1];

    const int block = blockIdx.x;                  // 2048 blocks
    const int b     = block >> 10;                 // HW/64 = 1024 per batch
    const int p0    = (block & 1023) * 64;         // 64 consecutive pixels
    const int tid   = threadIdx.x;
    const int px    = tid & 63;
    const int g     = tid >> 6;                    // wave 0..3

    const float* sb = src + (size_t)b * C * HW;
    #pragma unroll
    for (int k = 0; k < 8; ++k) {
        const int ch = k * 4 + g;                  // covers 0..31
        lds[ch][px] = sb[(size_t)ch * HW + p0 + px];   // 256B coalesced / wave
    }
    __syncthreads();

    #pragma unroll
    for (int k = 0; k < 8; ++k) {
        const int e  = k * 256 + tid;              // 0..2047
        const int pl = e >> 5;                     // pixel within tile
        const int ch = e & 31;                     // channel
        const int q  = ch >> 3;                    // quarter
        const int c  = ch & 7;
        float* dq = ws + (((size_t)q * BS + b) * HW + p0 + pl) * 8 + c;
        __builtin_nontemporal_store(lds[ch][pl], dq);  // 32B chunks, no L2 hold
    }
}

// ---------------------------------------------------------------------------
// Kernel 2: gather + 5x5 patch sum, one (b, quarter) combo per XCD.
// blk&7 = combo (XCD round-robin heuristic). Per-XCD read set: 2.1 MB quarter
// + 0.75 MB nnf < 4 MiB L2. Output stores are nontemporal so the write
// stream doesn't evict the gather-resident lines.
// 2 lanes per pixel, one float4 each: 32B row fully consumed, no over-fetch.
// ---------------------------------------------------------------------------
__global__ __launch_bounds__(256) void gather_sum_q(
    const float* __restrict__ ws,     // quarter-planes (q, b, hw, 8)
    const float* __restrict__ nnf,    // (b, 3, h, w)
    float* __restrict__ out) {        // (b, c, h, w)
    const unsigned blk   = blockIdx.x;         // 4096 blocks
    const unsigned combo = blk & 7u;           // -> XCD
    const unsigned b     = combo >> 2;         // batch
    const unsigned q     = combo & 3u;         // channel quarter
    const unsigned tile  = blk >> 3;           // 0..511
    const unsigned tid   = threadIdx.x;
    const unsigned k     = tid & 1u;           // float4 within 32B row
    const unsigned p     = tile * 128u + (tid >> 1);   // pixel 0..65535

    const float* nb = nnf + (size_t)b * 3 * HW;
    const float ci = nb[p];                    // row coord
    const float cj = nb[HW + p];               // col coord
    const float a  = nb[2 * HW + p];           // angle in [0,1)

    // Match XLA: sin(a*pi_f32)/cos via ocml; block FMA contraction everywhere
    const float arg = __fmul_rn(a, PI_F);
    const float s = sinf(arg);
    const float c = cosf(arg);

    const float4* tb = (const float4*)(ws + ((size_t)q * BS + b) * HW * 8) + k;

    float4 acc = make_float4(0.f, 0.f, 0.f, 0.f);
    #pragma unroll
    for (int i = 0; i < PS; ++i) {
        #pragma unroll
        for (int j = 0; j < PS; ++j) {
            const float fi = (float)(i - 2);       // pi_j = xx = i-2
            const float fj = (float)(j - 2);       // pi_i = yy = j-2
            // iR = (j-2)*s - (i-2)*c ; jR = (j-2)*c - (i-2)*s  (no contraction)
            const float iR = __fsub_rn(__fmul_rn(fj, s), __fmul_rn(fi, c));
            const float jR = __fsub_rn(__fmul_rn(fj, c), __fmul_rn(fi, s));
            float pr = __fadd_rn(ci, iR);
            float pc = __fadd_rn(cj, jR);
            pr = fminf(fmaxf(pr, 0.0f), (float)(H - 1));
            pc = fminf(fmaxf(pc, 0.0f), (float)(W - 1));
            const int row = (int)pr;               // trunc == floor (>=0)
            const int col = (int)pc;
            const int idx = (row << 8) + col;
            const float4 v = tb[idx * 2];          // 32B row / 2 lanes
            acc.x += v.x; acc.y += v.y; acc.z += v.z; acc.w += v.w;
        }
    }

    float* ob = out + ((size_t)b * C + q * 8 + k * 4) * HW + p;
    __builtin_nontemporal_store(acc.x, ob);
    __builtin_nontemporal_store(acc.y, ob + HW);
    __builtin_nontemporal_store(acc.z, ob + 2 * (size_t)HW);
    __builtin_nontemporal_store(acc.w, ob + 3 * (size_t)HW);
}

extern "C" void kernel_launch(void* const* d_in, const int* in_sizes, int n_in,
                              void* d_out, int out_size, void* d_ws, size_t ws_size,
                              hipStream_t stream) {
    const float* src = (const float*)d_in[0];   // (2, 32, 256, 256) f32
    const float* nnf = (const float*)d_in[1];   // (2, 3, 256, 256) f32
    float* out = (float*)d_out;                 // (2, 32, 256, 256) f32
    float* ws  = (float*)d_ws;                  // needs 16.8 MB

    transpose_split4<<<BS * (HW / 64), 256, 0, stream>>>(src, ws);
    gather_sum_q<<<4096, 256, 0, stream>>>(ws, nnf, out);
}

// Round 4
// 89.722 us; speedup vs baseline: 1.3504x; 1.3504x over previous
//
#include <hip/hip_runtime.h>
#include <hip/hip_fp16.h>
#include <math.h>

#define BS 2
#define C  32
#define H  256
#define W  256
#define HW (H * W)
#define PS 5

// f32(pi), matching JAX's rounding of np.pi to float32
#define PI_F 3.14159274101257324e+00f

// ws: fp16 staged source, layout (b, h*w, 32ch). Row = 64B = ONE cache line
// per gather point (4x fewer random line-requests than the 32B-quarter
// scheme). Per-batch plane = 4.19 MB -> fits one XCD's 4 MiB L2.

// ---------------------------------------------------------------------------
// Kernel 1: transpose + f32->fp16 convert: (b,c,h,w) f32 -> (b,hw,32) fp16.
// LDS stride 65 keeps both phases at <=2-way bank aliasing (free).
// Write phase: each thread packs 8 fp16 -> one uint4 (16B) store, tile
// region fully contiguous.
// ---------------------------------------------------------------------------
__global__ __launch_bounds__(256) void transpose_f16(
    const float* __restrict__ src, __half* __restrict__ ws) {
    __shared__ float lds[C][65];

    const int block = blockIdx.x;                  // 2048 blocks
    const int b     = block >> 10;                 // 1024 tiles per batch
    const int p0    = (block & 1023) * 64;         // 64 consecutive pixels
    const int tid   = threadIdx.x;
    const int px    = tid & 63;
    const int g     = tid >> 6;                    // wave 0..3

    const float* sb = src + (size_t)b * C * HW;
    #pragma unroll
    for (int k = 0; k < 8; ++k) {
        const int ch = k * 4 + g;                  // covers 0..31
        lds[ch][px] = sb[(size_t)ch * HW + p0 + px];   // 256B coalesced / wave
    }
    __syncthreads();

    const int pl = tid >> 2;                       // pixel within tile 0..63
    const int q  = tid & 3;                        // channel octet 0..3
    union { uint4 u4; __half2 h2[4]; } pk;
    #pragma unroll
    for (int i = 0; i < 4; ++i)
        pk.h2[i] = __floats2half2_rn(lds[q * 8 + 2 * i][pl],
                                     lds[q * 8 + 2 * i + 1][pl]);
    // halfs offset: pixel row (64B) + 16B octet
    uint4* dst = (uint4*)(ws + ((size_t)b * HW + p0 + pl) * 32) + q;
    *dst = pk.u4;                                  // 4KB contiguous per tile
}

// ---------------------------------------------------------------------------
// Kernel 2: gather + 5x5 patch sum from fp16 rows.
// blk&1 = batch -> XCD parity pinning: each XCD's random-gather set is one
// 4.19 MB batch plane (L2-resident, ~25 touches/line). 4 lanes/pixel, one
// uint4 (8 fp16) each -> the 64B row is exactly one line request.
// f32 accumulation; output stores nontemporal (write-only stream, don't
// evict gather lines from L2).
// ---------------------------------------------------------------------------
__global__ __launch_bounds__(256) void gather_f16(
    const __half* __restrict__ ws,    // (b, hw, 32) fp16
    const float* __restrict__ nnf,    // (b, 3, h, w)
    float* __restrict__ out) {        // (b, c, h, w)
    const unsigned blk  = blockIdx.x;          // 2048 blocks
    const unsigned b    = blk & 1u;            // batch -> XCD parity
    const unsigned tile = blk >> 1;            // 0..1023
    const unsigned tid  = threadIdx.x;
    const unsigned k    = tid & 3u;            // uint4 octet (ch 8k..8k+7)
    const unsigned p    = tile * 64u + (tid >> 2);   // pixel 0..65535

    const float* nb = nnf + (size_t)b * 3 * HW;
    const float ci = nb[p];                    // row coord
    const float cj = nb[HW + p];               // col coord
    const float a  = nb[2 * HW + p];           // angle in [0,1)

    // Match XLA: sin(a*pi_f32)/cos via ocml; block FMA contraction everywhere
    const float arg = __fmul_rn(a, PI_F);
    const float s = sinf(arg);
    const float c = cosf(arg);

    // Precompute all 25 indices (registers) so loads can issue in batches.
    int idxs[PS * PS];
    #pragma unroll
    for (int i = 0; i < PS; ++i) {
        #pragma unroll
        for (int j = 0; j < PS; ++j) {
            const float fi = (float)(i - 2);       // pi_j = xx = i-2
            const float fj = (float)(j - 2);       // pi_i = yy = j-2
            // iR = (j-2)*s - (i-2)*c ; jR = (j-2)*c - (i-2)*s (no contraction)
            const float iR = __fsub_rn(__fmul_rn(fj, s), __fmul_rn(fi, c));
            const float jR = __fsub_rn(__fmul_rn(fj, c), __fmul_rn(fi, s));
            float pr = __fadd_rn(ci, iR);
            float pc = __fadd_rn(cj, jR);
            pr = fminf(fmaxf(pr, 0.0f), (float)(H - 1));
            pc = fminf(fmaxf(pc, 0.0f), (float)(W - 1));
            idxs[i * PS + j] = (((int)pr) << 8) + (int)pc;   // trunc==floor
        }
    }

    const uint4* tb = (const uint4*)(ws + (size_t)b * HW * 32) + k;

    float acc[8] = {0.f, 0.f, 0.f, 0.f, 0.f, 0.f, 0.f, 0.f};
    #pragma unroll
    for (int t = 0; t < PS * PS; ++t) {
        union { uint4 u4; __half2 h2[4]; } v;
        v.u4 = tb[(size_t)idxs[t] * 4];            // 16B of the 64B row
        #pragma unroll
        for (int m = 0; m < 4; ++m) {
            const float2 f = __half22float2(v.h2[m]);
            acc[2 * m]     += f.x;
            acc[2 * m + 1] += f.y;
        }
    }

    float* ob = out + ((size_t)b * C + k * 8) * HW + p;
    #pragma unroll
    for (int m = 0; m < 8; ++m)
        __builtin_nontemporal_store(acc[m], ob + (size_t)m * HW);
}

extern "C" void kernel_launch(void* const* d_in, const int* in_sizes, int n_in,
                              void* d_out, int out_size, void* d_ws, size_t ws_size,
                              hipStream_t stream) {
    const float* src = (const float*)d_in[0];   // (2, 32, 256, 256) f32
    const float* nnf = (const float*)d_in[1];   // (2, 3, 256, 256) f32
    float* out = (float*)d_out;                 // (2, 32, 256, 256) f32
    __half* ws = (__half*)d_ws;                 // needs 8.4 MB

    transpose_f16<<<BS * (HW / 64), 256, 0, stream>>>(src, ws);
    gather_f16<<<BS * (HW / 64), 256, 0, stream>>>(ws, nnf, out);
}